// Round 6
// baseline (313.729 us; speedup 1.0000x reference)
//
#include <hip/hip_runtime.h>
#include <hip/hip_bf16.h>

// CausalSelfAttention on gfx950: bf16 MFMA pipeline, flash v3.
// x(4,2048,1024)f32, Wqkv(1024,3072)f32, Wproj(1024,1024)f32
// out = [ y (8192*1024) | k (4,16,2048,64) | v (4,16,2048,64) ] fp32
//
// R6: qkv is mixed-BW-bound (~2.3 TB/s over ~190-210MB across all 6 prior
// structures). Byte cuts: (1) kb dropped -- flash stages K from f32 outk
// (identical numerics); (2) operand-role swap: 256-side = Wqkv^T, 128-side
// = x -> FETCH ~86->~65MB (R2/R4 evidence) + d-contiguous float4 epilogue
// stores. Same proven 4-phase core. proj/prep unchanged.

typedef __bf16 bf16;
typedef __attribute__((ext_vector_type(8))) __bf16 bf16x8;
typedef __attribute__((ext_vector_type(4))) __bf16 bf16x4;
typedef __attribute__((ext_vector_type(4))) float f32x4;

#define AS_G __attribute__((address_space(1)))
#define AS_L __attribute__((address_space(3)))

// q pre-scale: 1/sqrt(64) * log2(e)  (softmax done in base-2)
#define QSCALE 0.1803368801111204f

__device__ __forceinline__ void gld_lds16(const bf16* g, bf16* l) {
  __builtin_amdgcn_global_load_lds((const AS_G void*)g, (AS_L void*)l, 16, 0, 0);
}

#define BAR() __builtin_amdgcn_s_barrier()
#define LGKM0() asm volatile("s_waitcnt lgkmcnt(0)" ::: "memory")
#define VMC(n) asm volatile("s_waitcnt vmcnt(" #n ")" ::: "memory")

// ---------- fused prep: cast x (f32->bf16) + transpose both weights ----------
__global__ __launch_bounds__(256) void k_prep(const float* __restrict__ x, bf16* __restrict__ xb,
                                              const float* __restrict__ Wqkv, bf16* __restrict__ wqkvT,
                                              const float* __restrict__ Wproj, bf16* __restrict__ wprojT) {
  __shared__ float tile[32][33];
  const int bid = blockIdx.x, tid = threadIdx.x;
  if (bid < 4096) {  // cast: 8 elems/thread
    int i = (bid * 256 + tid) * 8;
    float4 a = *(const float4*)(x + i);
    float4 b = *(const float4*)(x + i + 4);
    bf16x8 o;
    o[0] = (bf16)a.x; o[1] = (bf16)a.y; o[2] = (bf16)a.z; o[3] = (bf16)a.w;
    o[4] = (bf16)b.x; o[5] = (bf16)b.y; o[6] = (bf16)b.z; o[7] = (bf16)b.w;
    *(bf16x8*)(xb + i) = o;
    return;
  }
  const float* in; bf16* out; int N, t;
  if (bid < 7168) { t = bid - 4096; N = 3072; in = Wqkv; out = wqkvT; }
  else            { t = bid - 7168; N = 1024; in = Wproj; out = wprojT; }
  const int nbx = N >> 5;
  const int bx = (t % nbx) * 32, by = (t / nbx) * 32;
  const int tx = tid & 31, ty = tid >> 5;  // (32,8)
#pragma unroll
  for (int i = 0; i < 4; ++i)
    tile[ty + i * 8][tx] = in[(size_t)(by + ty + i * 8) * N + bx + tx];
  __syncthreads();
#pragma unroll
  for (int i = 0; i < 4; ++i)
    out[(size_t)(bx + ty + i * 8) * 1024 + by + tx] = (bf16)tile[tx][ty + i * 8];
}

// ---------------- 256x128 4-phase counted-vmcnt GEMM mainloop ----------------
// A-side = 256 rows (4 segs), B-side = 128 rows (2 segs), BK=64, both stride
// 1024. 512 threads = 8 waves; per-wave 64(A) x 64(B). 3-buffer LDS 144KB,
// stage t+2, vmcnt(6) boundary. Zero-conflict chunk-XOR layout (verified).
__device__ __forceinline__ void gemm_main_256x128(const bf16* __restrict__ A,
                                                  const bf16* __restrict__ Bt,
                                                  int m0, int n0,
                                                  bf16* As, bf16* Bs,
                                                  f32x4 acc[4][4]) {
  const int tid = threadIdx.x;
  const int w = tid >> 6, lane = tid & 63, lo = lane & 15, hi = lane >> 4;
  const int wm = w >> 1, wn = w & 1;
  const int urow = tid >> 3;
  const int gsw = (tid & 7) ^ (urow & 7);
  const bf16* ga = A + (size_t)(m0 + urow) * 1024 + gsw * 8;
  const bf16* gb = Bt + (size_t)(n0 + urow) * 1024 + gsw * 8;
  const int p0 = hi ^ (lo & 7);
  const int aRow = wm * 64 + lo;
  const int bRow = wn * 64 + lo;

#define STAGE_A2(t, bufi, s0) do {                                                              \
    gld_lds16(ga + (size_t)(s0) * 65536 + (t) * 64,                                             \
              As + (bufi) * 16384 + (s0) * 4096 + w * 512);                                     \
    gld_lds16(ga + (size_t)((s0) + 1) * 65536 + (t) * 64,                                       \
              As + (bufi) * 16384 + ((s0) + 1) * 4096 + w * 512);                               \
  } while (0)
#define STAGE_B2(t, bufi) do {                                                                  \
    gld_lds16(gb + (t) * 64, Bs + (bufi) * 8192 + w * 512);                                     \
    gld_lds16(gb + 65536 + (t) * 64, Bs + (bufi) * 8192 + 4096 + w * 512);                      \
  } while (0)

  STAGE_A2(0, 0, 0); STAGE_A2(0, 0, 2); STAGE_B2(0, 0);
  STAGE_A2(1, 1, 0); STAGE_A2(1, 1, 2); STAGE_B2(1, 1);

  bf16x8 a[2][2], b[4][2];
  int buf = 0, sbuf = 2;
#pragma unroll 1
  for (int t = 0; t < 16; ++t) {
    if (t < 15) { VMC(6); } else { VMC(0); }
    BAR();
    const bf16* Ab = As + buf * 16384;
    const bf16* Bb = Bs + buf * 8192;

#pragma unroll
    for (int mi = 0; mi < 2; ++mi) {
      const bf16* r = Ab + (aRow + mi * 16) * 64;
      a[mi][0] = *(const bf16x8*)(r + p0 * 8);
      a[mi][1] = *(const bf16x8*)(r + (p0 ^ 4) * 8);
    }
#pragma unroll
    for (int ni = 0; ni < 2; ++ni) {
      const bf16* r = Bb + (bRow + ni * 16) * 64;
      b[ni][0] = *(const bf16x8*)(r + p0 * 8);
      b[ni][1] = *(const bf16x8*)(r + (p0 ^ 4) * 8);
    }
    if (t < 14) STAGE_A2(t + 2, sbuf, 0);
    BAR();
    __builtin_amdgcn_s_setprio(1);
#pragma unroll
    for (int ks = 0; ks < 2; ++ks)
#pragma unroll
      for (int mi = 0; mi < 2; ++mi)
#pragma unroll
        for (int ni = 0; ni < 2; ++ni)
          acc[mi][ni] = __builtin_amdgcn_mfma_f32_16x16x32_bf16(a[mi][ks], b[ni][ks], acc[mi][ni], 0, 0, 0);
    __builtin_amdgcn_s_setprio(0);
    BAR();

#pragma unroll
    for (int ni = 0; ni < 2; ++ni) {
      const bf16* r = Bb + (bRow + (ni + 2) * 16) * 64;
      b[ni + 2][0] = *(const bf16x8*)(r + p0 * 8);
      b[ni + 2][1] = *(const bf16x8*)(r + (p0 ^ 4) * 8);
    }
    if (t < 14) STAGE_A2(t + 2, sbuf, 2);
    BAR();
    __builtin_amdgcn_s_setprio(1);
#pragma unroll
    for (int ks = 0; ks < 2; ++ks)
#pragma unroll
      for (int mi = 0; mi < 2; ++mi)
#pragma unroll
        for (int ni = 0; ni < 2; ++ni)
          acc[mi][ni + 2] = __builtin_amdgcn_mfma_f32_16x16x32_bf16(a[mi][ks], b[ni + 2][ks], acc[mi][ni + 2], 0, 0, 0);
    __builtin_amdgcn_s_setprio(0);
    BAR();

#pragma unroll
    for (int mi = 0; mi < 2; ++mi) {
      const bf16* r = Ab + (aRow + (mi + 2) * 16) * 64;
      a[mi][0] = *(const bf16x8*)(r + p0 * 8);
      a[mi][1] = *(const bf16x8*)(r + (p0 ^ 4) * 8);
    }
    if (t < 14) STAGE_B2(t + 2, sbuf);
    BAR();
    __builtin_amdgcn_s_setprio(1);
#pragma unroll
    for (int ks = 0; ks < 2; ++ks)
#pragma unroll
      for (int mi = 0; mi < 2; ++mi)
#pragma unroll
        for (int ni = 0; ni < 2; ++ni)
          acc[mi + 2][ni + 2] = __builtin_amdgcn_mfma_f32_16x16x32_bf16(a[mi][ks], b[ni + 2][ks], acc[mi + 2][ni + 2], 0, 0, 0);
    __builtin_amdgcn_s_setprio(0);
    BAR();

    __builtin_amdgcn_s_setprio(1);
#pragma unroll
    for (int ks = 0; ks < 2; ++ks)
#pragma unroll
      for (int mi = 0; mi < 2; ++mi)
#pragma unroll
        for (int ni = 0; ni < 2; ++ni)
          acc[mi + 2][ni] = __builtin_amdgcn_mfma_f32_16x16x32_bf16(a[mi][ks], b[ni][ks], acc[mi + 2][ni], 0, 0, 0);
    __builtin_amdgcn_s_setprio(0);

    buf = (buf == 2) ? 0 : buf + 1;
    sbuf = (sbuf == 2) ? 0 : sbuf + 1;
  }
#undef STAGE_A2
#undef STAGE_B2
}

// -------- GEMM1 (role-swapped): A-side = Wqkv^T (256 cols), B-side = x (128 rows).
// C frag: row = w-col (hi*4+r), col = x-row (lo) -> d-contiguous stores.
__global__ __launch_bounds__(512, 2) void k_gemm_qkv(const bf16* __restrict__ xb,
                                                     const bf16* __restrict__ WqkvT,
                                                     bf16* __restrict__ qb,
                                                     bf16* __restrict__ vtb,
                                                     float* __restrict__ outk, float* __restrict__ outv) {
  __shared__ bf16 As[49152], Bs[24576];  // 144 KB
  // grid 768 = 64 x-tiles(128) x 12 w-tiles(256); XCD swizzle (768%8==0):
  // per XCD: 8 consecutive x-tiles x all 12 w-tiles (x-panel 2MB L2-resident).
  int id = blockIdx.x;
  int swz = (id & 7) * 96 + (id >> 3);
  int byx = swz / 12, bxw = swz - byx * 12;
  int xrow0 = byx * 128, wcol0 = bxw * 256;
  f32x4 acc[4][4] = {};
  gemm_main_256x128(WqkvT, xb, wcol0, xrow0, As, Bs, acc);
  const int tid = threadIdx.x;
  const int w = tid >> 6, lane = tid & 63, lo = lane & 15, hi = lane >> 4;
  const int wm = w >> 1, wn = w & 1;  // wm over A-side (w-cols), wn over B-side (x-rows)
#pragma unroll
  for (int mi = 0; mi < 4; ++mi) {
    int gcb = wcol0 + wm * 64 + mi * 16 + hi * 4;  // w-col base (+r), 0..3071
    int part = gcb >> 10;                          // 0=q 1=k 2=v (uniform per block)
    int cc = gcb & 1023, h = cc >> 6, d0 = cc & 63;
#pragma unroll
    for (int ni = 0; ni < 4; ++ni) {
      int grow = xrow0 + wn * 64 + ni * 16 + lo;   // x-row = b*2048 + t
      int bb = grow >> 11, t = grow & 2047;
      size_t idx0 = ((size_t)(bb * 16 + h) * 2048 + t) * 64 + d0;
      if (part == 0) {
        bf16x4 pk;
#pragma unroll
        for (int r = 0; r < 4; ++r) pk[r] = (bf16)(acc[mi][ni][r] * QSCALE);
        *(bf16x4*)(qb + idx0) = pk;
      } else if (part == 1) {
        float4 f;
        f.x = acc[mi][ni][0]; f.y = acc[mi][ni][1]; f.z = acc[mi][ni][2]; f.w = acc[mi][ni][3];
        *(float4*)(outk + idx0) = f;
      } else {
        float4 f;
        f.x = acc[mi][ni][0]; f.y = acc[mi][ni][1]; f.z = acc[mi][ni][2]; f.w = acc[mi][ni][3];
        *(float4*)(outv + idx0) = f;
#pragma unroll
        for (int r = 0; r < 4; ++r)
          vtb[((size_t)(bb * 16 + h) * 64 + d0 + r) * 2048 + t] = (bf16)acc[mi][ni][r];
      }
    }
  }
}

// ---------------- GEMM2: out_y = y_att @ Wproj (unchanged) ----------------
__global__ __launch_bounds__(512, 2) void k_gemm_proj(const bf16* __restrict__ yb,
                                                      const bf16* __restrict__ WprojT,
                                                      float* __restrict__ out) {
  __shared__ bf16 As[49152], Bs[24576];  // 144 KB
  int id = blockIdx.x;
  int swz = (id & 7) * 32 + (id >> 3);   // 256 % 8 == 0
  int by = swz >> 3, bx = swz & 7;
  int m0 = by * 256, n0 = bx * 128;
  f32x4 acc[4][4] = {};
  gemm_main_256x128(yb, WprojT, m0, n0, As, Bs, acc);
  const int tid = threadIdx.x;
  const int w = tid >> 6, lane = tid & 63, lo = lane & 15, hi = lane >> 4;
  const int wm = w >> 1, wn = w & 1;
#pragma unroll
  for (int mi = 0; mi < 4; ++mi)
#pragma unroll
    for (int ni = 0; ni < 4; ++ni)
#pragma unroll
      for (int r = 0; r < 4; ++r) {
        int grow = m0 + wm * 64 + mi * 16 + hi * 4 + r;
        int gcol = n0 + wn * 64 + ni * 16 + lo;
        out[(size_t)grow * 1024 + gcol] = acc[mi][ni][r];
      }
}

// ---------------- flash v3: K staged from f32 outk (reg-staged, T14 split) ----------------
#define PSTR 76

__device__ __forceinline__ void p_store(f32x4 sacc[4], bool mask,
                                        int w, int lo, int hi, bf16* psrow) {
  if (mask) {
#pragma unroll
    for (int nt = 0; nt < 4; ++nt)
#pragma unroll
      for (int r = 0; r < 4; ++r)
        if (nt * 16 + hi * 4 + r > w * 16 + lo) sacc[nt][r] = -1e30f;
  }
#pragma unroll
  for (int nt = 0; nt < 4; ++nt) {
    bf16x4 pk;
#pragma unroll
    for (int r = 0; r < 4; ++r) pk[r] = (bf16)__builtin_amdgcn_exp2f(sacc[nt][r]);
    *(bf16x4*)(psrow + (w * 16 + lo) * PSTR + nt * 16 + hi * 4) = pk;
  }
}

__device__ __forceinline__ void write_y(bf16* __restrict__ y, int b, int h, int qrow,
                                        int hi, const f32x4 o[4], float inv) {
  size_t base = ((size_t)b * 2048 + qrow) * 1024 + h * 64;
#pragma unroll
  for (int mt = 0; mt < 4; ++mt) {
    bf16x4 yk;
#pragma unroll
    for (int r = 0; r < 4; ++r) yk[r] = (bf16)(o[mt][r] * inv);
    *(bf16x4*)(y + base + mt * 16 + hi * 4) = yk;
  }
}

__global__ __launch_bounds__(256, 4) void k_flash(const bf16* __restrict__ q,
                                                  const float* __restrict__ kf32,
                                                  const bf16* __restrict__ vt,
                                                  bf16* __restrict__ y) {
  __shared__ bf16 Ks[2 * 4096];      // [buf][s][d], chunk-swizzled by s&7
  __shared__ bf16 Vs[2 * 4096];      // [buf][d][s] (V^T), chunk-swizzled by d&7
  __shared__ bf16 Ones[16 * 64];     // row 0 = 1.0, rows 1..15 = 0 (l-row operand)
  __shared__ bf16 Ps[128 * PSTR];    // [q_local][s]: rows 0..63 tile A, 64..127 tile B
  const int bi = blockIdx.x;
  const int slot = bi >> 3;
  const int bh = (bi & 7) + 8 * (slot >> 4);
  const int v = slot & 15;
  const int j = ((bi >> 8) & 1) ? (15 - v) : v;
  const int jA = j, jB = 31 - j;
  const int tid = threadIdx.x, w = tid >> 6, lane = tid & 63, lo = lane & 15, hi = lane >> 4;
  const bf16* qp = q + (size_t)bh * 2048 * 64;
  const float* kp = kf32 + (size_t)bh * 2048 * 64;
  const bf16* vtp = vt + (size_t)bh * 64 * 2048;

  // K staging geometry: 2 passes; pass p handles chunk (row,c) with
  // u=tid+256p, row=u>>3, c=u&7. Source f32 is linear (coalesced); dest
  // chunk XOR-swizzled: LDS[row][c^(row&7)] = global[row][c] (same layout
  // as the old pre-swizzled-source gld_lds path).
  const int krow0 = tid >> 3, kc0 = tid & 7;
  const int krow1 = (tid + 256) >> 3, kc1 = tid & 7;

  {
    int rr = tid >> 4, c = (tid & 15) * 4;
    bf16x4 z;
    bf16 v1 = (rr == 0) ? (bf16)1.0f : (bf16)0.0f;
    z[0] = v1; z[1] = v1; z[2] = v1; z[3] = v1;
    *(bf16x4*)(Ones + rr * 64 + c) = z;
  }

  // prologue: issue K f32 loads + V gld_lds for tile 0
  float4 kr[4];
  {
    const float* s0p = kp + (size_t)krow0 * 64 + kc0 * 8;
    const float* s1p = kp + (size_t)krow1 * 64 + kc1 * 8;
    kr[0] = *(const float4*)s0p; kr[1] = *(const float4*)(s0p + 4);
    kr[2] = *(const float4*)s1p; kr[3] = *(const float4*)(s1p + 4);
#pragma unroll
    for (int p = 0; p < 2; ++p) {
      int u = tid + 256 * p;
      int row = u >> 3, g = (u & 7) ^ (row & 7);
      gld_lds16(vtp + (size_t)row * 2048 + g * 8, Vs + p * 2048 + w * 512);
    }
  }

  bf16x8 qfA[2], qfB[2];
  {
    int qA = jA * 64 + w * 16 + lo;
    int qB = jB * 64 + w * 16 + lo;
    qfA[0] = *(const bf16x8*)(qp + (size_t)qA * 64 + hi * 8);
    qfA[1] = *(const bf16x8*)(qp + (size_t)qA * 64 + 32 + hi * 8);
    qfB[0] = *(const bf16x8*)(qp + (size_t)qB * 64 + hi * 8);
    qfB[1] = *(const bf16x8*)(qp + (size_t)qB * 64 + 32 + hi * 8);
  }
  f32x4 oA[4] = {}, oB[4] = {};
  f32x4 oLA = {}, oLB = {};

  VMC(0);
  // write prologue K (buf 0)
  {
#pragma unroll
    for (int p = 0; p < 2; ++p) {
      int row = p ? krow1 : krow0, c = p ? kc1 : kc0;
      bf16x8 kk;
#pragma unroll
      for (int e = 0; e < 4; ++e) { kk[e] = (bf16)kr[2 * p][e]; kk[4 + e] = (bf16)kr[2 * p + 1][e]; }
      *(bf16x8*)(Ks + row * 64 + (c ^ (row & 7)) * 8) = kk;
    }
  }
  LGKM0();
  BAR();

  for (int st = 0; st <= jB; ++st) {
    const int cb = (st & 1) * 4096;
    const int nb = cb ^ 4096;

    bf16x8 kf[4][2];
#pragma unroll
    for (int nt = 0; nt < 4; ++nt)
#pragma unroll
      for (int ks = 0; ks < 2; ++ks)
        kf[nt][ks] = *(const bf16x8*)(Ks + cb + (nt * 16 + lo) * 64 + ((ks * 4 + hi) ^ (lo & 7)) * 8);

    // async-stage tile st+1: V via gld_lds; K via f32 reg loads (issued now,
    // converted+written after PV -- HBM latency hides under QK^T+softmax+PV)
    if (st < jB) {
      const int s1 = (st + 1) * 64;
      const float* s0p = kp + (size_t)(s1 + krow0) * 64 + kc0 * 8;
      const float* s1p = kp + (size_t)(s1 + krow1) * 64 + kc1 * 8;
      kr[0] = *(const float4*)s0p; kr[1] = *(const float4*)(s0p + 4);
      kr[2] = *(const float4*)s1p; kr[3] = *(const float4*)(s1p + 4);
#pragma unroll
      for (int p = 0; p < 2; ++p) {
        int u = tid + 256 * p;
        int row = u >> 3, g = (u & 7) ^ (row & 7);
        gld_lds16(vtp + (size_t)row * 2048 + s1 + g * 8, Vs + nb + p * 2048 + w * 512);
      }
    }

    const bool actA = (st <= jA);
    f32x4 saccA[4] = {}, saccB[4] = {};
    __builtin_amdgcn_s_setprio(1);
    if (actA) {
#pragma unroll
      for (int nt = 0; nt < 4; ++nt)
#pragma unroll
        for (int ks = 0; ks < 2; ++ks)
          saccA[nt] = __builtin_amdgcn_mfma_f32_16x16x32_bf16(kf[nt][ks], qfA[ks], saccA[nt], 0, 0, 0);
    }
#pragma unroll
    for (int nt = 0; nt < 4; ++nt)
#pragma unroll
      for (int ks = 0; ks < 2; ++ks)
        saccB[nt] = __builtin_amdgcn_mfma_f32_16x16x32_bf16(kf[nt][ks], qfB[ks], saccB[nt], 0, 0, 0);
    __builtin_amdgcn_s_setprio(0);
    if (actA) p_store(saccA, st == jA, w, lo, hi, Ps);
    p_store(saccB, st == jB, w, lo, hi, Ps + 64 * PSTR);
    LGKM0();

    bf16x8 pfA[2], pfB[2];
#pragma unroll
    for (int ks = 0; ks < 2; ++ks) {
      pfB[ks] = *(const bf16x8*)(Ps + (64 + w * 16 + lo) * PSTR + ks * 32 + hi * 8);
      if (actA) pfA[ks] = *(const bf16x8*)(Ps + (w * 16 + lo) * PSTR + ks * 32 + hi * 8);
    }
    __builtin_amdgcn_s_setprio(1);
#pragma unroll
    for (int mt = 0; mt < 5; ++mt) {
#pragma unroll
      for (int ks = 0; ks < 2; ++ks) {
        int row = mt * 16 + lo;
        bf16x8 vf = (mt < 4)
            ? *(const bf16x8*)(Vs + cb + row * 64 + ((ks * 4 + hi) ^ (row & 7)) * 8)
            : *(const bf16x8*)(Ones + lo * 64 + ((ks * 4 + hi) ^ (lo & 7)) * 8);
        if (mt < 4) {
          oB[mt] = __builtin_amdgcn_mfma_f32_16x16x32_bf16(vf, pfB[ks], oB[mt], 0, 0, 0);
          if (actA) oA[mt] = __builtin_amdgcn_mfma_f32_16x16x32_bf16(vf, pfA[ks], oA[mt], 0, 0, 0);
        } else {
          oLB = __builtin_amdgcn_mfma_f32_16x16x32_bf16(vf, pfB[ks], oLB, 0, 0, 0);
          if (actA) oLA = __builtin_amdgcn_mfma_f32_16x16x32_bf16(vf, pfA[ks], oLA, 0, 0, 0);
        }
      }
    }
    __builtin_amdgcn_s_setprio(0);

    // drain V gld_lds + my K f32 loads; convert+write K into nb; make the
    // ds_writes visible (LGKM0) before the buffer-rotation barrier.
    VMC(0);
    if (st < jB) {
#pragma unroll
      for (int p = 0; p < 2; ++p) {
        int row = p ? krow1 : krow0, c = p ? kc1 : kc0;
        bf16x8 kk;
#pragma unroll
        for (int e = 0; e < 4; ++e) { kk[e] = (bf16)kr[2 * p][e]; kk[4 + e] = (bf16)kr[2 * p + 1][e]; }
        *(bf16x8*)(Ks + nb + row * 64 + (c ^ (row & 7)) * 8) = kk;
      }
    }
    LGKM0();
    BAR();
  }

  const int b = bh >> 4, h = bh & 15;
  float lA = __shfl(oLA[0], lo, 64);
  float lB = __shfl(oLB[0], lo, 64);
  write_y(y, b, h, jA * 64 + w * 16 + lo, hi, oA, 1.0f / lA);
  write_y(y, b, h, jB * 64 + w * 16 + lo, hi, oB, 1.0f / lB);
}

// ---------------------------------------------------------------------------
extern "C" void kernel_launch(void* const* d_in, const int* in_sizes, int n_in,
                              void* d_out, int out_size, void* d_ws, size_t ws_size,
                              hipStream_t stream) {
  const float* x = (const float*)d_in[0];
  const float* Wqkv = (const float*)d_in[1];
  const float* Wproj = (const float*)d_in[2];
  float* out = (float*)d_out;

  const size_t YSZ = (size_t)8192 * 1024;
  char* ws = (char*)d_ws;
  bf16* xb = (bf16*)ws;      ws += (size_t)8192 * 1024 * 2;
  bf16* wqkvT = (bf16*)ws;   ws += (size_t)3072 * 1024 * 2;
  bf16* wprojT = (bf16*)ws;  ws += (size_t)1024 * 1024 * 2;
  bf16* qb = (bf16*)ws;      ws += (size_t)64 * 2048 * 64 * 2;
  bf16* vtb = (bf16*)ws;     ws += (size_t)64 * 2048 * 64 * 2;
  bf16* yb = (bf16*)ws;      // 71 MB total

  float* outy = out;
  float* outk = out + YSZ;
  float* outv = out + 2 * YSZ;

  k_prep<<<8192, 256, 0, stream>>>(x, xb, Wqkv, wqkvT, Wproj, wprojT);
  k_gemm_qkv<<<768, 512, 0, stream>>>(xb, wqkvT, qb, vtb, outk, outv);
  k_flash<<<1024, 256, 0, stream>>>(qb, outk, vtb, yb);
  k_gemm_proj<<<256, 512, 0, stream>>>(yb, wprojT, outy);
}